// Round 1
// baseline (1607.607 us; speedup 1.0000x reference)
//
#include <hip/hip_runtime.h>
#include <stdint.h>

// Problem constants
#define BB   4
#define SS   2048
#define HIDD 2048
#define NH   16
#define HD   128

typedef float  floatx4 __attribute__((ext_vector_type(4)));
typedef __bf16 bf16x8  __attribute__((ext_vector_type(8)));
typedef unsigned short ushort8  __attribute__((ext_vector_type(8)));
typedef unsigned short ushort4v __attribute__((ext_vector_type(4)));

__device__ __forceinline__ uint16_t f2bf(float f) {
  uint32_t u = __builtin_bit_cast(uint32_t, f);
  u += 0x7FFFu + ((u >> 16) & 1u);   // RNE
  return (uint16_t)(u >> 16);
}

__device__ __forceinline__ floatx4 mfma16(bf16x8 a, bf16x8 b, floatx4 c) {
  return __builtin_amdgcn_mfma_f32_16x16x32_bf16(a, b, c, 0, 0, 0);
}

#if __has_builtin(__builtin_amdgcn_exp2f)
#define EXP2F(x) __builtin_amdgcn_exp2f(x)
#else
#define EXP2F(x) exp2f(x)
#endif

// ---------------- fp32 -> bf16 convert (vector x4) ----------------
__global__ void cvt_f32_bf16(const float* __restrict__ src, uint16_t* __restrict__ dst) {
  int idx = (blockIdx.x * 256 + threadIdx.x) * 4;
  const float4 v = *reinterpret_cast<const float4*>(src + idx);
  ushort4v o = { f2bf(v.x), f2bf(v.y), f2bf(v.z), f2bf(v.w) };
  *reinterpret_cast<ushort4v*>(dst + idx) = o;
}

// ---------------- bf16 GEMM: C[M,N] = A[M,K] * W[N,K]^T ----------------
// 128x128 block tile, 4 waves in 2x2 grid, each wave 64x64 via 4x4 MFMA tiles.
// LDS layout: element (row, k) at row*32 + ((kc ^ ((row>>1)&3))*8 + (k&7)),
// kc = k>>3  -> conflict-lean b128 reads AND writes.
// modes: 0=Q (bf16 [B,H,S,D], scaled) 1=K (bf16 [B,H,S,D] + fp32 cache c=0)
//        2=V (bf16 [B,H,D,S] + fp32 cache c=1) 3=O (fp32 [M,N])
__global__ __launch_bounds__(256) void gemm_bf16(
    const uint16_t* __restrict__ A,
    const uint16_t* __restrict__ Bw,
    uint16_t* __restrict__ outb,
    float* __restrict__ outf,
    int mode, float scl)
{
  __shared__ alignas(16) uint16_t lsA[128 * 32];
  __shared__ alignas(16) uint16_t lsB[128 * 32];

  const int t    = threadIdx.x;
  const int lane = t & 63;
  const int wv   = t >> 6;
  const int wx   = wv & 1;
  const int wy   = wv >> 1;
  const int l15  = lane & 15;
  const int lk   = lane >> 4;
  const int m0   = blockIdx.y * 128;
  const int n0   = blockIdx.x * 128;

  const int srow = t >> 2;   // staging row base (0..63), +64 on 2nd chunk
  const int skc  = t & 3;    // staging k-chunk

  floatx4 acc[4][4];
  #pragma unroll
  for (int i = 0; i < 4; i++)
    #pragma unroll
    for (int j = 0; j < 4; j++) acc[i][j] = floatx4{0.f, 0.f, 0.f, 0.f};

  const uint16_t* Ag = A  + (size_t)m0 * HIDD;
  const uint16_t* Bg = Bw + (size_t)n0 * HIDD;

  for (int k0 = 0; k0 < HIDD; k0 += 32) {
    #pragma unroll
    for (int i = 0; i < 2; ++i) {
      int row = srow + i * 64;
      ushort8 va = *reinterpret_cast<const ushort8*>(Ag + (size_t)row * HIDD + k0 + skc * 8);
      ushort8 vb = *reinterpret_cast<const ushort8*>(Bg + (size_t)row * HIDD + k0 + skc * 8);
      int sw = (skc ^ ((row >> 1) & 3)) << 3;
      *reinterpret_cast<ushort8*>(&lsA[row * 32 + sw]) = va;
      *reinterpret_cast<ushort8*>(&lsB[row * 32 + sw]) = vb;
    }
    __syncthreads();

    bf16x8 af[4], bf[4];
    #pragma unroll
    for (int mi = 0; mi < 4; mi++) {
      int row = wy * 64 + mi * 16 + l15;
      af[mi] = *reinterpret_cast<const bf16x8*>(&lsA[row * 32 + ((lk ^ ((row >> 1) & 3)) << 3)]);
    }
    #pragma unroll
    for (int nj = 0; nj < 4; nj++) {
      int row = wx * 64 + nj * 16 + l15;
      bf[nj] = *reinterpret_cast<const bf16x8*>(&lsB[row * 32 + ((lk ^ ((row >> 1) & 3)) << 3)]);
    }
    #pragma unroll
    for (int mi = 0; mi < 4; mi++)
      #pragma unroll
      for (int nj = 0; nj < 4; nj++)
        acc[mi][nj] = mfma16(af[mi], bf[nj], acc[mi][nj]);
    __syncthreads();
  }

  // Epilogue. C layout: col = lane&15, row = (lane>>4)*4 + reg  [verified m89/m91]
  #pragma unroll
  for (int mi = 0; mi < 4; mi++) {
    int rbase = m0 + wy * 64 + mi * 16 + lk * 4;
    #pragma unroll
    for (int nj = 0; nj < 4; nj++) {
      int col = n0 + wx * 64 + nj * 16 + l15;
      floatx4 v = acc[mi][nj];
      #pragma unroll
      for (int r = 0; r < 4; r++) {
        int rr = rbase + r;
        float val = v[r] * scl;
        int b_ = rr >> 11, s_ = rr & 2047;
        int h_ = col >> 7, d_ = col & 127;
        size_t bh = (size_t)(b_ * NH + h_);
        if (mode == 0) {
          outb[(bh * SS + s_) * HD + d_] = f2bf(val);
        } else if (mode == 1) {
          outb[(bh * SS + s_) * HD + d_] = f2bf(val);
          outf[((bh * 2 + 0) * SS + s_) * HD + d_] = val;
        } else if (mode == 2) {
          outb[(bh * HD + d_) * SS + s_] = f2bf(val);
          outf[((bh * 2 + 1) * SS + s_) * HD + d_] = val;
        } else {
          outf[(size_t)rr * HIDD + col] = val;
        }
      }
    }
  }
}

// ---------------- causal flash attention ----------------
// grid (S/64, B*H), 256 thr = 4 waves; wave w owns q rows qblk*64+w*16 .. +15.
// q pre-scaled by D^-0.5*log2(e) -> softmax in exp2 domain.
__global__ __launch_bounds__(256) void attn_fwd(
    const uint16_t* __restrict__ qb,
    const uint16_t* __restrict__ kb,
    const uint16_t* __restrict__ vtb,
    uint16_t* __restrict__ ctxb)
{
  const int qblk = blockIdx.x;
  const int bh   = blockIdx.y;
  const int b    = bh >> 4;
  const int h    = bh & 15;
  const int t    = threadIdx.x;
  const int lane = t & 63;
  const int w    = t >> 6;
  const int l15  = lane & 15;
  const int lk   = lane >> 4;

  const int qrow0 = qblk * 64 + w * 16;
  const uint16_t* qptr = qb  + ((size_t)bh * SS + qrow0) * HD;
  const uint16_t* kptr = kb  + (size_t)bh * SS * HD;
  const uint16_t* vptr = vtb + (size_t)bh * (size_t)HD * SS;

  bf16x8 qf[4];
  #pragma unroll
  for (int c = 0; c < 4; c++)
    qf[c] = *reinterpret_cast<const bf16x8*>(qptr + (size_t)l15 * HD + c * 32 + lk * 8);

  floatx4 o[8];
  #pragma unroll
  for (int i = 0; i < 8; i++) o[i] = floatx4{0.f, 0.f, 0.f, 0.f};
  float m2[4], lsum[4];
  #pragma unroll
  for (int r = 0; r < 4; r++) { m2[r] = -__builtin_inff(); lsum[r] = 0.f; }

  __shared__ alignas(16) uint16_t pls[4][16 * 40];  // per-wave P buffer, stride 40
  uint16_t* pbuf = pls[w];

  const int ktiles = (qrow0 >> 5) + 1;
  for (int kt = 0; kt < ktiles; ++kt) {
    const int kbase = kt * 32;
    floatx4 s0 = {0.f, 0.f, 0.f, 0.f}, s1 = {0.f, 0.f, 0.f, 0.f};
    #pragma unroll
    for (int c = 0; c < 4; c++) {
      bf16x8 k0f = *reinterpret_cast<const bf16x8*>(kptr + (size_t)(kbase + l15) * HD + c * 32 + lk * 8);
      bf16x8 k1f = *reinterpret_cast<const bf16x8*>(kptr + (size_t)(kbase + 16 + l15) * HD + c * 32 + lk * 8);
      s0 = mfma16(qf[c], k0f, s0);
      s1 = mfma16(qf[c], k1f, s1);
    }
    if (kbase + 31 > qrow0) {  // partial tile: causal mask (key > query -> -inf)
      #pragma unroll
      for (int r = 0; r < 4; r++) {
        int qr = qrow0 + lk * 4 + r;
        if (kbase + l15 > qr)      s0[r] = -__builtin_inff();
        if (kbase + 16 + l15 > qr) s1[r] = -__builtin_inff();
      }
    }
    float alpha[4];
    #pragma unroll
    for (int r = 0; r < 4; r++) {
      float mt = fmaxf(s0[r], s1[r]);
      #pragma unroll
      for (int off = 1; off < 16; off <<= 1) mt = fmaxf(mt, __shfl_xor(mt, off));
      float mn = fmaxf(m2[r], mt);
      alpha[r] = EXP2F(m2[r] - mn);
      m2[r] = mn;
    }
    float p0[4], p1[4];
    #pragma unroll
    for (int r = 0; r < 4; r++) {
      p0[r] = EXP2F(s0[r] - m2[r]);
      p1[r] = EXP2F(s1[r] - m2[r]);
      float ps = p0[r] + p1[r];
      #pragma unroll
      for (int off = 1; off < 16; off <<= 1) ps += __shfl_xor(ps, off);
      lsum[r] = lsum[r] * alpha[r] + ps;
    }
    #pragma unroll
    for (int i = 0; i < 8; i++)
      #pragma unroll
      for (int r = 0; r < 4; r++) o[i][r] *= alpha[r];

    // P: C-layout -> A-layout via LDS round trip (wave-private, lockstep)
    #pragma unroll
    for (int r = 0; r < 4; r++) {
      pbuf[(lk * 4 + r) * 40 + l15]      = f2bf(p0[r]);
      pbuf[(lk * 4 + r) * 40 + 16 + l15] = f2bf(p1[r]);
    }
    asm volatile("s_waitcnt lgkmcnt(0)" ::: "memory");
    bf16x8 pf = *reinterpret_cast<const bf16x8*>(pbuf + l15 * 40 + lk * 8);

    #pragma unroll
    for (int i = 0; i < 8; i++) {
      bf16x8 vf = *reinterpret_cast<const bf16x8*>(vptr + (size_t)(i * 16 + l15) * SS + kbase + lk * 8);
      o[i] = mfma16(pf, vf, o[i]);
    }
  }

  float inv[4];
  #pragma unroll
  for (int r = 0; r < 4; r++) inv[r] = 1.0f / lsum[r];
  uint16_t* cdst = ctxb + ((size_t)b * SS + qrow0) * HIDD + h * HD;
  #pragma unroll
  for (int i = 0; i < 8; i++)
    #pragma unroll
    for (int r = 0; r < 4; r++)
      cdst[(size_t)(lk * 4 + r) * HIDD + i * 16 + l15] = f2bf(o[i][r] * inv[r]);
}

// ---------------- launch ----------------
extern "C" void kernel_launch(void* const* d_in, const int* in_sizes, int n_in,
                              void* d_out, int out_size, void* d_ws, size_t ws_size,
                              hipStream_t stream) {
  const float* x  = (const float*)d_in[0];
  const float* Wq = (const float*)d_in[1];
  const float* Wk = (const float*)d_in[2];
  const float* Wv = (const float*)d_in[3];
  const float* Wo = (const float*)d_in[4];
  float* out = (float*)d_out;
  float* kv  = out + (size_t)BB * SS * HIDD;  // kv cache region

  uint8_t* ws = (uint8_t*)d_ws;
  // byte offsets (total 160 MiB)
  uint16_t* xb  = (uint16_t*)(ws);              // 32 MiB; reused as ctx after attn
  uint16_t* qb  = (uint16_t*)(ws + 33554432);
  uint16_t* kb  = (uint16_t*)(ws + 67108864);
  uint16_t* vtb = (uint16_t*)(ws + 100663296);
  uint16_t* wqb = (uint16_t*)(ws + 134217728);
  uint16_t* wkb = (uint16_t*)(ws + 142606336);
  uint16_t* wvb = (uint16_t*)(ws + 150994944);
  uint16_t* wob = (uint16_t*)(ws + 159383552);

  const float QSCALE = 0.08838834764831845f * 1.4426950408889634f; // D^-0.5 * log2(e)

  cvt_f32_bf16<<<16384, 256, 0, stream>>>(x,  xb);
  cvt_f32_bf16<<<4096,  256, 0, stream>>>(Wq, wqb);
  cvt_f32_bf16<<<4096,  256, 0, stream>>>(Wk, wkb);
  cvt_f32_bf16<<<4096,  256, 0, stream>>>(Wv, wvb);
  cvt_f32_bf16<<<4096,  256, 0, stream>>>(Wo, wob);

  dim3 ggrid(HIDD / 128, (BB * SS) / 128);  // (16, 64)
  gemm_bf16<<<ggrid, 256, 0, stream>>>(xb, wqb, qb,  nullptr, 0, QSCALE);
  gemm_bf16<<<ggrid, 256, 0, stream>>>(xb, wkb, kb,  kv,      1, 1.0f);
  gemm_bf16<<<ggrid, 256, 0, stream>>>(xb, wvb, vtb, kv,      2, 1.0f);

  attn_fwd<<<dim3(SS / 64, BB * NH), 256, 0, stream>>>(qb, kb, vtb, xb /*ctx*/);

  gemm_bf16<<<ggrid, 256, 0, stream>>>(xb, wob, nullptr, out, 3, 1.0f);
}